// Round 5
// baseline (1048.940 us; speedup 1.0000x reference)
//
#include <hip/hip_runtime.h>

// GraphSAGE 3-layer eval on MI355X (gfx950).
// Layer l: agg = segment_sum(in[src], dst, n_dst); h = in[:n_dst]@Wself + agg@Wneigh + b; relu (l<2)
// Sizes: N0=400000, N1=100000, N2=25000, N3=6250, E0=1.6M, E1=400k, E2=100k, D=H=256, C=47.
//
// R5: distinct kernel names per layer (profiling attribution); GEMM stages 2x32-K subtiles
//     per barrier pair (halves barrier drains); conv_x+wconv fused; agg 8-deep unroll.
// Note: harness restore/poison (~1.6GB ws fill + 410MB x restore) is ~400-500us of dur_us.

#define DIM 256
#define CAP 64

typedef __attribute__((ext_vector_type(8))) short bf16x8;
typedef __attribute__((ext_vector_type(4))) float f32x4;

__device__ __forceinline__ short f2bf(float f) {
    union { float f; unsigned u; } v; v.f = f;
    unsigned r = v.u + 0x7FFF + ((v.u >> 16) & 1);   // round-to-nearest-even
    return (short)(r >> 16);
}
__device__ __forceinline__ float bf2f(unsigned short h) {
    union { unsigned u; float f; } v; v.u = ((unsigned)h) << 16;
    return v.f;
}

#define GPTR(p) ((const __attribute__((address_space(1))) void*)(p))
#define LPTR(p) ((__attribute__((address_space(3))) void*)(p))

// ---------------- prep: x f32->bf16 convert (blocks < cb) + weight transpose (rest) ----------------
__global__ __launch_bounds__(256) void prep_kernel(
    const float* __restrict__ x, short* __restrict__ xb, int n4, int cb,
    const float* __restrict__ ws0, const float* __restrict__ wn0,
    const float* __restrict__ ws1, const float* __restrict__ wn1,
    const float* __restrict__ ws2, const float* __restrict__ wn2,
    short* t0, short* t1, short* t2, short* t3, short* t4, short* t5)
{
    if ((int)blockIdx.x < cb) {
        int i = blockIdx.x * 256 + threadIdx.x;
        const int stride = cb * 256;
        for (; i < n4; i += stride) {
            const float4 v = ((const float4*)x)[i];
            short4 o;
            o.x = f2bf(v.x); o.y = f2bf(v.y); o.z = f2bf(v.z); o.w = f2bf(v.w);
            ((short4*)xb)[i] = o;
        }
        return;
    }
    int idx = (blockIdx.x - cb) * 256 + threadIdx.x;   // 0 .. 327680
    const float* src; short* dst; int N, base;
    if (idx < 65536)       { src = ws0; dst = t0; N = 256; base = 0; }
    else if (idx < 131072) { src = wn0; dst = t1; N = 256; base = 65536; }
    else if (idx < 196608) { src = ws1; dst = t2; N = 256; base = 131072; }
    else if (idx < 262144) { src = wn1; dst = t3; N = 256; base = 196608; }
    else if (idx < 294912) { src = ws2; dst = t4; N = 47;  base = 262144; }
    else if (idx < 327680) { src = wn2; dst = t5; N = 47;  base = 294912; }
    else return;
    const int l = idx - base;
    const int n = l >> 8, k = l & 255;
    dst[(size_t)n * 256 + k] = f2bf(n < N ? src[(size_t)k * N + n] : 0.f);
}

// ---------------- edge bucketing, all 3 layers in one launch ----------------
__global__ __launch_bounds__(256) void bucket_edges(
    const int* __restrict__ src0, const int* __restrict__ dst0, int E0,
    const int* __restrict__ src1, const int* __restrict__ dst1, int E1,
    const int* __restrict__ src2, const int* __restrict__ dst2, int E2,
    int* __restrict__ cur0, int* __restrict__ cur1, int* __restrict__ cur2,
    int* __restrict__ bk0, int* __restrict__ bk1, int* __restrict__ bk2)
{
    int e = blockIdx.x * 256 + threadIdx.x;
    const int* s; const int* d; int* cur; int* bk;
    if (e < E0)           { s = src0; d = dst0; cur = cur0; bk = bk0; }
    else if (e < E0 + E1) { e -= E0; s = src1; d = dst1; cur = cur1; bk = bk1; }
    else if (e < E0 + E1 + E2) { e -= E0 + E1; s = src2; d = dst2; cur = cur2; bk = bk2; }
    else return;
    const int dd = d[e];
    const int pos = atomicAdd(&cur[dd], 1);
    if (pos < CAP) bk[(size_t)dd * CAP + pos] = s[e];
}

// ---------------- gather aggregation: one wave per dst, bf16 output ----------------
template<int LAYER, bool F32IN>
__global__ __launch_bounds__(256) void agg_kernel(
    const void* __restrict__ Xv,
    const int* __restrict__ bucket,
    const int* __restrict__ cursor,
    short* __restrict__ agg,
    int n_dst)
{
    const int wave = (blockIdx.x << 2) + (threadIdx.x >> 6);
    if (wave >= n_dst) return;
    const int lane = threadIdx.x & 63;
    int deg = cursor[wave];
    if (deg > CAP) deg = CAP;
    const int* bk = bucket + (size_t)wave * CAP;

    float a0 = 0.f, a1 = 0.f, a2 = 0.f, a3 = 0.f;
    int j = 0;
    if (F32IN) {
        const float* X = (const float*)Xv;
        for (; j + 4 <= deg; j += 4) {
            const int s0 = bk[j], s1 = bk[j + 1], s2 = bk[j + 2], s3 = bk[j + 3];
            const float4 v0 = *(const float4*)(X + (size_t)s0 * DIM + lane * 4);
            const float4 v1 = *(const float4*)(X + (size_t)s1 * DIM + lane * 4);
            const float4 v2 = *(const float4*)(X + (size_t)s2 * DIM + lane * 4);
            const float4 v3 = *(const float4*)(X + (size_t)s3 * DIM + lane * 4);
            a0 += (v0.x + v1.x) + (v2.x + v3.x);
            a1 += (v0.y + v1.y) + (v2.y + v3.y);
            a2 += (v0.z + v1.z) + (v2.z + v3.z);
            a3 += (v0.w + v1.w) + (v2.w + v3.w);
        }
        for (; j < deg; ++j) {
            const float4 v0 = *(const float4*)(X + (size_t)bk[j] * DIM + lane * 4);
            a0 += v0.x; a1 += v0.y; a2 += v0.z; a3 += v0.w;
        }
    } else {
        const unsigned short* X = (const unsigned short*)Xv;
        for (; j + 8 <= deg; j += 8) {
            ushort4 u[8];
#pragma unroll
            for (int q = 0; q < 8; ++q)
                u[q] = *(const ushort4*)(X + (size_t)bk[j + q] * DIM + lane * 4);
#pragma unroll
            for (int q = 0; q < 8; ++q) {
                a0 += bf2f(u[q].x); a1 += bf2f(u[q].y);
                a2 += bf2f(u[q].z); a3 += bf2f(u[q].w);
            }
        }
        for (; j + 2 <= deg; j += 2) {
            const ushort4 u0 = *(const ushort4*)(X + (size_t)bk[j] * DIM + lane * 4);
            const ushort4 u1 = *(const ushort4*)(X + (size_t)bk[j + 1] * DIM + lane * 4);
            a0 += bf2f(u0.x) + bf2f(u1.x);
            a1 += bf2f(u0.y) + bf2f(u1.y);
            a2 += bf2f(u0.z) + bf2f(u1.z);
            a3 += bf2f(u0.w) + bf2f(u1.w);
        }
        if (j < deg) {
            const ushort4 u0 = *(const ushort4*)(X + (size_t)bk[j] * DIM + lane * 4);
            a0 += bf2f(u0.x); a1 += bf2f(u0.y); a2 += bf2f(u0.z); a3 += bf2f(u0.w);
        }
    }
    short4 o; o.x = f2bf(a0); o.y = f2bf(a1); o.z = f2bf(a2); o.w = f2bf(a3);
    *(short4*)(agg + (size_t)wave * DIM + lane * 4) = o;
}

// ---------------- MFMA GEMM: C = A0@B0^T + A1@B1^T + bias (+relu) ----------------
// 128x128 tile, 256 thr = 4 waves (2x2 of 64x64). Two 32-K subtiles staged per barrier pair.
template<int LAYER, bool A0F32, bool RELU, bool OUTF32>
__global__ __launch_bounds__(256) void mfma_gemm(
    const void* __restrict__ A0v,
    const short* __restrict__ A1,
    const short* __restrict__ B0,
    const short* __restrict__ B1,
    const float* __restrict__ bias,
    void* __restrict__ Cv,
    int M, int NV)
{
    __shared__ short As[2][128 * 32];
    __shared__ short Bs[2][128 * 32];

    const int t  = threadIdx.x;
    const int bm = blockIdx.x * 128;
    const int bn = blockIdx.y * 128;

    const int srow = t >> 2;            // 0..63
    const int scol = (t & 3) << 3;      // 0,8,16,24 (shorts)
    const int wv   = t >> 6;

    const int wm = (wv & 1) << 6;
    const int wn = (wv >> 1) << 6;
    const int lr = t & 15;
    const int lq = (t & 63) >> 4;

    int gmA = bm + srow;        if (gmA >= M) gmA = M - 1;
    int gmA2 = bm + srow + 64;  if (gmA2 >= M) gmA2 = M - 1;

    f32x4 acc[4][4];
#pragma unroll
    for (int i = 0; i < 4; ++i)
#pragma unroll
        for (int j = 0; j < 4; ++j) {
            acc[i][j][0] = 0.f; acc[i][j][1] = 0.f; acc[i][j][2] = 0.f; acc[i][j][3] = 0.f;
        }

    for (int half = 0; half < 2; ++half) {
        const short* Bh = half ? B1 : B0;
        for (int kb = 0; kb < 256; kb += 64) {
#pragma unroll
            for (int sub = 0; sub < 2; ++sub) {
                const int kk = kb + sub * 32;
                if (A0F32 && half == 0) {
                    const float* A = (const float*)A0v;
#pragma unroll
                    for (int i = 0; i < 2; ++i) {
                        const int gm = i ? gmA2 : gmA;
                        const int row = srow + i * 64;
                        const float* g = A + (size_t)gm * 256 + kk + scol;
                        const float4 u = *(const float4*)g;
                        const float4 w = *(const float4*)(g + 4);
                        bf16x8 pk;
                        pk[0] = f2bf(u.x); pk[1] = f2bf(u.y); pk[2] = f2bf(u.z); pk[3] = f2bf(u.w);
                        pk[4] = f2bf(w.x); pk[5] = f2bf(w.y); pk[6] = f2bf(w.z); pk[7] = f2bf(w.w);
                        *(bf16x8*)(&As[sub][row * 32 + scol]) = pk;
                    }
                } else {
                    const short* Ah = half ? A1 : (const short*)A0v;
                    __builtin_amdgcn_global_load_lds(GPTR(Ah + (size_t)gmA  * 256 + kk + scol),
                                                     LPTR(&As[sub][0]    + wv * 512), 16, 0, 0);
                    __builtin_amdgcn_global_load_lds(GPTR(Ah + (size_t)gmA2 * 256 + kk + scol),
                                                     LPTR(&As[sub][2048] + wv * 512), 16, 0, 0);
                }
                __builtin_amdgcn_global_load_lds(GPTR(Bh + (size_t)(bn + srow)      * 256 + kk + scol),
                                                 LPTR(&Bs[sub][0]    + wv * 512), 16, 0, 0);
                __builtin_amdgcn_global_load_lds(GPTR(Bh + (size_t)(bn + srow + 64) * 256 + kk + scol),
                                                 LPTR(&Bs[sub][2048] + wv * 512), 16, 0, 0);
            }
            __syncthreads();

#pragma unroll
            for (int sub = 0; sub < 2; ++sub) {
                bf16x8 af[4], bfr[4];
#pragma unroll
                for (int i = 0; i < 4; ++i)
                    af[i] = *(const bf16x8*)(&As[sub][(wm + i * 16 + lr) * 32 + lq * 8]);
#pragma unroll
                for (int i = 0; i < 4; ++i)
                    bfr[i] = *(const bf16x8*)(&Bs[sub][(wn + i * 16 + lr) * 32 + lq * 8]);
#pragma unroll
                for (int mt = 0; mt < 4; ++mt)
#pragma unroll
                    for (int nt = 0; nt < 4; ++nt)
                        acc[mt][nt] = __builtin_amdgcn_mfma_f32_16x16x32_bf16(af[mt], bfr[nt], acc[mt][nt], 0, 0, 0);
            }
            __syncthreads();
        }
    }

#pragma unroll
    for (int nt = 0; nt < 4; ++nt) {
        const int gn = bn + wn + nt * 16 + lr;
        const float bv = bias[gn < NV ? gn : 0];
#pragma unroll
        for (int mt = 0; mt < 4; ++mt) {
            const f32x4 a = acc[mt][nt];
#pragma unroll
            for (int r = 0; r < 4; ++r) {
                const int gm = bm + wm + mt * 16 + lq * 4 + r;
                if (gm < M && gn < NV) {
                    float v = a[r] + bv;
                    if (RELU) v = fmaxf(v, 0.f);
                    if (OUTF32) ((float*)Cv)[(size_t)gm * NV + gn] = v;
                    else        ((short*)Cv)[(size_t)gm * NV + gn] = f2bf(v);
                }
            }
        }
    }
}

extern "C" void kernel_launch(void* const* d_in, const int* in_sizes, int n_in,
                              void* d_out, int out_size, void* d_ws, size_t ws_size,
                              hipStream_t stream) {
    (void)n_in; (void)out_size;

    const float* x    = (const float*)d_in[0];
    const int*   src0 = (const int*)d_in[1];
    const int*   dst0 = (const int*)d_in[2];
    const int*   src1 = (const int*)d_in[3];
    const int*   dst1 = (const int*)d_in[4];
    const int*   src2 = (const int*)d_in[5];
    const int*   dst2 = (const int*)d_in[6];
    const float* ws0  = (const float*)d_in[7];
    const float* wn0  = (const float*)d_in[8];
    const float* b0   = (const float*)d_in[9];
    const float* ws1  = (const float*)d_in[10];
    const float* wn1  = (const float*)d_in[11];
    const float* b1   = (const float*)d_in[12];
    const float* ws2  = (const float*)d_in[13];
    const float* wn2  = (const float*)d_in[14];
    const float* b2   = (const float*)d_in[15];

    const int E0 = in_sizes[1];
    const int E1 = in_sizes[3];
    const int E2 = in_sizes[5];
    const int N0 = 400000, N1 = 100000, N2 = 25000, N3 = 6250;

    char* p = (char*)d_ws;
    auto alloc = [&](size_t bytes) { char* r = p; p += (bytes + 255) & ~(size_t)255; return r; };
    short* h0   = (short*)alloc((size_t)N1 * DIM * 2);
    short* h1   = (short*)alloc((size_t)N2 * DIM * 2);
    short* agg  = (short*)alloc((size_t)N1 * DIM * 2);
    int*   bk0  = (int*)alloc((size_t)N1 * CAP * 4);
    int*   bk1  = (int*)alloc((size_t)N2 * CAP * 4);
    int*   bk2  = (int*)alloc((size_t)N3 * CAP * 4);
    int*   curs = (int*)alloc((size_t)(N1 + N2 + N3) * 4);
    short* wt0s = (short*)alloc(256 * 256 * 2);
    short* wt0n = (short*)alloc(256 * 256 * 2);
    short* wt1s = (short*)alloc(256 * 256 * 2);
    short* wt1n = (short*)alloc(256 * 256 * 2);
    short* wt2s = (short*)alloc(128 * 256 * 2);
    short* wt2n = (short*)alloc(128 * 256 * 2);
    const size_t base_bytes = (size_t)(p - (char*)d_ws);
    const size_t xbf_bytes  = (size_t)N0 * DIM * 2;
    const bool   use_xbf    = (base_bytes + xbf_bytes) <= ws_size;
    short* x_bf = (short*)alloc(xbf_bytes);

    int* cur0 = curs, *cur1 = curs + N1, *cur2 = curs + N1 + N2;
    const int Etot = E0 + E1 + E2;
    const int conv_blocks = use_xbf ? 8192 : 0;

    prep_kernel<<<conv_blocks + 1280, 256, 0, stream>>>(
        x, x_bf, N0 * DIM / 4, conv_blocks,
        ws0, wn0, ws1, wn1, ws2, wn2, wt0s, wt0n, wt1s, wt1n, wt2s, wt2n);
    hipMemsetAsync(curs, 0, (size_t)(N1 + N2 + N3) * 4, stream);
    bucket_edges<<<(Etot + 255) / 256, 256, 0, stream>>>(
        src0, dst0, E0, src1, dst1, E1, src2, dst2, E2,
        cur0, cur1, cur2, bk0, bk1, bk2);

    // ---- layer 0 ----
    if (use_xbf) {
        agg_kernel<0, false><<<(N1 + 3) / 4, 256, 0, stream>>>(x_bf, bk0, cur0, agg, N1);
        mfma_gemm<0, false, true, false><<<dim3((N1 + 127) / 128, 2), 256, 0, stream>>>(
            x_bf, agg, wt0s, wt0n, b0, h0, N1, 256);
    } else {
        agg_kernel<0, true><<<(N1 + 3) / 4, 256, 0, stream>>>(x, bk0, cur0, agg, N1);
        mfma_gemm<0, true, true, false><<<dim3((N1 + 127) / 128, 2), 256, 0, stream>>>(
            x, agg, wt0s, wt0n, b0, h0, N1, 256);
    }
    // ---- layer 1 ----
    agg_kernel<1, false><<<(N2 + 3) / 4, 256, 0, stream>>>(h0, bk1, cur1, agg, N2);
    mfma_gemm<1, false, true, false><<<dim3((N2 + 127) / 128, 2), 256, 0, stream>>>(
        h0, agg, wt1s, wt1n, b1, h1, N2, 256);
    // ---- layer 2 ----
    agg_kernel<2, false><<<(N3 + 3) / 4, 256, 0, stream>>>(h1, bk2, cur2, agg, N3);
    mfma_gemm<2, false, false, true><<<dim3((N3 + 127) / 128, 1), 256, 0, stream>>>(
        h1, agg, wt2s, wt2n, b2, d_out, N3, 47);
}